// Round 2
// baseline (20851.831 us; speedup 1.0000x reference)
//
#include <hip/hip_runtime.h>
#include <cstdint>
#include <cstddef>

// Problem constants
#define BB 32
#define TT 512
#define FF 1280
#define HH 512
// derived: M = BB*TT = 16384, N = 3072 (2 dirs * 3 gates * 512), C = 1024

static __device__ __forceinline__ float sigm(float x) {
    x = fminf(30.f, fmaxf(-30.f, x));
    return 1.f / (1.f + __expf(-x));
}
static __device__ __forceinline__ float tanh_fast(float x) {
    x = fminf(15.f, fmaxf(-15.f, x));
    const float e = __expf(2.f * x);
    return (e - 1.f) / (e + 1.f);
}

// ---------------------------------------------------------------------------
// GEMM: xg[d][b][t][g][j] = sum_k A'[m][k] * W[n][k] + bias[n]
//   A' = A (layer 0) or BN(A) = A*bn_scale[k]+bn_shift[k] fused at load.
//   A: [16384][K] row-major, W: [3072][K] row-major (dir-major),
//   m = b*512 + t, n = d*1536 + g*512 + j
// 128x128 block tile, BK=16, 256 threads, 8x8 acc/thread.
// LDS inner dim padded 128->132 (16B-aligned; stage-write conflict 4->2 way).
// ---------------------------------------------------------------------------
__global__ __launch_bounds__(256, 2) void gemm_xg(
    const float* __restrict__ A, const float* __restrict__ W,
    const float* __restrict__ bias, const float* __restrict__ bn_scale,
    const float* __restrict__ bn_shift, float* __restrict__ xg, int K)
{
    __shared__ float As[16][132];
    __shared__ float Ws[16][132];
    const int tid = threadIdx.x;
    const int tx = tid & 15, ty = tid >> 4;
    const int m0 = blockIdx.x * 128, n0 = blockIdx.y * 128;

    float acc[8][8];
#pragma unroll
    for (int i = 0; i < 8; ++i)
#pragma unroll
        for (int j = 0; j < 8; ++j) acc[i][j] = 0.f;

    const int sr = tid >> 2;       // 0..63 (row within half-tile)
    const int sk = (tid & 3) * 4;  // 0,4,8,12 (k offset)

    for (int k0 = 0; k0 < K; k0 += 16) {
        float4 sc4, sh4;
        if (bn_scale) {
            sc4 = *(const float4*)&bn_scale[k0 + sk];
            sh4 = *(const float4*)&bn_shift[k0 + sk];
        }
#pragma unroll
        for (int it = 0; it < 2; ++it) {
            const int r = sr + it * 64;
            float4 a = *(const float4*)&A[(size_t)(m0 + r) * K + k0 + sk];
            if (bn_scale) {
                a.x = fmaf(a.x, sc4.x, sh4.x);
                a.y = fmaf(a.y, sc4.y, sh4.y);
                a.z = fmaf(a.z, sc4.z, sh4.z);
                a.w = fmaf(a.w, sc4.w, sh4.w);
            }
            As[sk + 0][r] = a.x; As[sk + 1][r] = a.y;
            As[sk + 2][r] = a.z; As[sk + 3][r] = a.w;
            const float4 w = *(const float4*)&W[(size_t)(n0 + r) * K + k0 + sk];
            Ws[sk + 0][r] = w.x; Ws[sk + 1][r] = w.y;
            Ws[sk + 2][r] = w.z; Ws[sk + 3][r] = w.w;
        }
        __syncthreads();
#pragma unroll
        for (int k = 0; k < 16; ++k) {
            const float4 a0 = *(const float4*)&As[k][ty * 4];
            const float4 a1 = *(const float4*)&As[k][64 + ty * 4];
            const float4 b0 = *(const float4*)&Ws[k][tx * 4];
            const float4 b1 = *(const float4*)&Ws[k][64 + tx * 4];
            const float ar[8] = {a0.x, a0.y, a0.z, a0.w, a1.x, a1.y, a1.z, a1.w};
            const float br[8] = {b0.x, b0.y, b0.z, b0.w, b1.x, b1.y, b1.z, b1.w};
#pragma unroll
            for (int i = 0; i < 8; ++i)
#pragma unroll
                for (int j = 0; j < 8; ++j)
                    acc[i][j] = fmaf(ar[i], br[j], acc[i][j]);
        }
        __syncthreads();
    }

    // Epilogue: n-tile never spans dir/gate boundaries (128 | 512).
    const int d = n0 / 1536;
    const int rem0 = n0 - d * 1536;
    const int g = rem0 >> 9;
    const int jj0 = rem0 & 511;
    const int b = m0 >> 9;       // m-tile never spans batch boundary (128 | 512)
    const int t0 = m0 & 511;
    const size_t base_db = (size_t)(d * 32 + b) * 786432 + (size_t)g * 512;

    float4 bias4[2];
#pragma unroll
    for (int ch = 0; ch < 2; ++ch)
        bias4[ch] = *(const float4*)&bias[d * 1536 + g * 512 + jj0 + ch * 64 + tx * 4];

#pragma unroll
    for (int ri = 0; ri < 8; ++ri) {
        const int t = t0 + (ri >> 2) * 64 + ty * 4 + (ri & 3);
        const size_t rowb = base_db + (size_t)t * 1536;
#pragma unroll
        for (int ch = 0; ch < 2; ++ch) {
            float4 v;
            v.x = acc[ri][ch * 4 + 0] + bias4[ch].x;
            v.y = acc[ri][ch * 4 + 1] + bias4[ch].y;
            v.z = acc[ri][ch * 4 + 2] + bias4[ch].z;
            v.w = acc[ri][ch * 4 + 3] + bias4[ch].w;
            *(float4*)&xg[rowb + (size_t)(jj0 + ch * 64 + tx * 4)] = v;
        }
    }
}

// ---------------------------------------------------------------------------
// Recurrent scan. Grid = 256 blocks x 256 threads (1 block/CU via 120KB LDS;
// all blocks co-resident). Block (dir, bg, jb) owns batches [bg*8, +8),
// h-columns [jb*16, +16). w_hh slice (96KB) resident in LDS for all 512 steps.
// Per step: stage h(t-1) (16KB) -> LDS, 4-way K-split partial dots, LDS
// reduce, gate math, write h slice + y; release flag. h double-buffered by
// step parity; consumers spin (relaxed) on the 32 producer flags of step t-1,
// then one acquire fence (buffer_inv) invalidates stale L1/L2.
// ---------------------------------------------------------------------------
__global__ __launch_bounds__(256, 1) void scan_gru(
    const float* __restrict__ xg,   // [2][32][512][3][512]
    const float* __restrict__ whh,  // [2][1536][512]
    const float* __restrict__ bhh,  // [2][1536]
    float* __restrict__ hglob,      // [2 parity][2 dir][4 bg][128][8][4]
    int* flags,                     // [2 dir][4 bg][32 jb][512 t]
    float* __restrict__ y)          // [16384][1024]
{
    __shared__ float w_lds[3][128][16][4];  // 96KB: [g][k4][jj][kk]
    __shared__ float h_lds[128][8][4];      // 16KB: [k4][b][kk]
    __shared__ float parts[4][8][8][6];     // 6KB:  [kq][b][jgrp][g*2+js]

    const int bid = blockIdx.x;
    const int dir = bid >> 7;
    const int bg = (bid >> 5) & 3;
    const int jb = bid & 31;
    const int tid = threadIdx.x;

    // Stage this block's w_hh rows {j, 512+j, 1024+j} for j in [jb*16, +16)
    for (int r = 0; r < 48; ++r) {
        const int g = r >> 4, jj = r & 15;
        const float* row = whh + ((size_t)dir * 1536 + g * 512 + jb * 16 + jj) * 512;
#pragma unroll
        for (int p = 0; p < 2; ++p) {
            const int k = p * 256 + tid;
            w_lds[g][k >> 2][jj][k & 3] = row[k];
        }
    }

    // compute-phase mapping (all 256 threads)
    const int cb = tid & 7;           // batch-local
    const int jgrp = (tid >> 3) & 7;  // owns 2 j-columns
    const int kq = tid >> 6;          // k quarter
    const int jj0 = jgrp * 2;
    // reduce-phase mapping (tid < 128)
    const int rjl = tid & 15, rb = tid >> 4;
    const int jglob = jb * 16 + rjl;

    float br_ = 0.f, bz_ = 0.f, bn_ = 0.f;
    if (tid < 128) {
        br_ = bhh[dir * 1536 + 0 * 512 + jglob];
        bz_ = bhh[dir * 1536 + 1 * 512 + jglob];
        bn_ = bhh[dir * 1536 + 2 * 512 + jglob];
    }
    const int flag_base = (dir * 4 + bg) * 32 * 512;
    __syncthreads();

    for (int t = 0; t < TT; ++t) {
        const int tt = (dir == 0) ? t : (TT - 1 - t);

        // prefetch xg for this step (issued before the spin)
        float xr = 0.f, xz = 0.f, xn = 0.f;
        if (tid < 128) {
            const size_t mb = (((size_t)dir * 32 + bg * 8 + rb) * 512 + tt) * 1536;
            xr = xg[mb + 0 * 512 + jglob];
            xz = xg[mb + 1 * 512 + jglob];
            xn = xg[mb + 2 * 512 + jglob];
        }

        if (t > 0) {
            if (tid < 32) {
                int* fp = flags + flag_base + tid * 512 + (t - 1);
                while (__hip_atomic_load(fp, __ATOMIC_RELAXED,
                                         __HIP_MEMORY_SCOPE_AGENT) == 0)
                    __builtin_amdgcn_s_sleep(2);
                __builtin_amdgcn_fence(__ATOMIC_ACQUIRE, "agent");
            }
            __syncthreads();
            // stage h(t-1): 16KB, parity (t-1)&1
            const float4* src = (const float4*)(hglob +
                (size_t)(((((t & 1) ^ 1) * 2 + dir) * 4 + bg)) * 4096);
            float4* dst = (float4*)h_lds;
#pragma unroll
            for (int i = 0; i < 4; ++i) dst[i * 256 + tid] = src[i * 256 + tid];
            __syncthreads();
        } else {
            float4* dst = (float4*)h_lds;
            const float4 z4 = make_float4(0.f, 0.f, 0.f, 0.f);
#pragma unroll
            for (int i = 0; i < 4; ++i) dst[i * 256 + tid] = z4;
            __syncthreads();
        }

        // partial dot products over this thread's k-quarter
        float p00 = 0, p01 = 0, p10 = 0, p11 = 0, p20 = 0, p21 = 0;
#pragma unroll 4
        for (int k4 = 0; k4 < 32; ++k4) {
            const int kk = kq * 32 + k4;
            const float4 h4 = *(const float4*)&h_lds[kk][cb][0];
            const float4 w0a = *(const float4*)&w_lds[0][kk][jj0][0];
            const float4 w0b = *(const float4*)&w_lds[0][kk][jj0 + 1][0];
            const float4 w1a = *(const float4*)&w_lds[1][kk][jj0][0];
            const float4 w1b = *(const float4*)&w_lds[1][kk][jj0 + 1][0];
            const float4 w2a = *(const float4*)&w_lds[2][kk][jj0][0];
            const float4 w2b = *(const float4*)&w_lds[2][kk][jj0 + 1][0];
            p00 = fmaf(h4.x, w0a.x, p00); p00 = fmaf(h4.y, w0a.y, p00);
            p00 = fmaf(h4.z, w0a.z, p00); p00 = fmaf(h4.w, w0a.w, p00);
            p01 = fmaf(h4.x, w0b.x, p01); p01 = fmaf(h4.y, w0b.y, p01);
            p01 = fmaf(h4.z, w0b.z, p01); p01 = fmaf(h4.w, w0b.w, p01);
            p10 = fmaf(h4.x, w1a.x, p10); p10 = fmaf(h4.y, w1a.y, p10);
            p10 = fmaf(h4.z, w1a.z, p10); p10 = fmaf(h4.w, w1a.w, p10);
            p11 = fmaf(h4.x, w1b.x, p11); p11 = fmaf(h4.y, w1b.y, p11);
            p11 = fmaf(h4.z, w1b.z, p11); p11 = fmaf(h4.w, w1b.w, p11);
            p20 = fmaf(h4.x, w2a.x, p20); p20 = fmaf(h4.y, w2a.y, p20);
            p20 = fmaf(h4.z, w2a.z, p20); p20 = fmaf(h4.w, w2a.w, p20);
            p21 = fmaf(h4.x, w2b.x, p21); p21 = fmaf(h4.y, w2b.y, p21);
            p21 = fmaf(h4.z, w2b.z, p21); p21 = fmaf(h4.w, w2b.w, p21);
        }
        {
            float* pp = &parts[kq][cb][jgrp][0];
            pp[0] = p00; pp[1] = p01; pp[2] = p10;
            pp[3] = p11; pp[4] = p20; pp[5] = p21;
        }
        __syncthreads();

        if (tid < 128) {
            const int jgr = rjl >> 1, js = rjl & 1;
            float gr = br_, gz = bz_, gn = bn_;
#pragma unroll
            for (int q = 0; q < 4; ++q) {
                gr += parts[q][rb][jgr][0 + js];
                gz += parts[q][rb][jgr][2 + js];
                gn += parts[q][rb][jgr][4 + js];
            }
            const float hold = h_lds[jglob >> 2][rb][jglob & 3];
            const float r = sigm(xr + gr);
            const float z = sigm(xz + gz);
            const float nn = tanh_fast(xn + r * gn);
            const float hnew = (1.f - z) * nn + z * hold;
            // y[m][c], m = b*512 + tt, c = dir*512 + j
            y[((size_t)(bg * 8 + rb) * 512 + tt) * 1024 + dir * 512 + jglob] = hnew;
            // h slice, parity t&1
            hglob[(size_t)(((t & 1) * 2 + dir) * 4 + bg) * 4096 +
                  (size_t)(jglob >> 2) * 32 + rb * 4 + (jglob & 3)] = hnew;
        }
        __syncthreads();   // drains all threads' h stores (vmcnt 0) before flag
        if (tid == 0) {
            __builtin_amdgcn_fence(__ATOMIC_RELEASE, "agent");  // buffer_wbl2
            __hip_atomic_store(flags + flag_base + jb * 512 + t, 1,
                               __ATOMIC_RELAXED, __HIP_MEMORY_SCOPE_AGENT);
        }
    }
}

// ---------------------------------------------------------------------------
// BatchNorm: partial sums -> finalize (scale/shift). Apply is fused into the
// next layer's GEMM A-load; only the final layer uses bn_apply_k -> d_out.
// ---------------------------------------------------------------------------
__global__ __launch_bounds__(256) void bn_stats_k(
    const float* __restrict__ y, float* __restrict__ part)
{
    const int ct = blockIdx.x;  // 0..7  (c tile of 128)
    const int mc = blockIdx.y;  // 0..31 (m chunk of 512)
    const int tid = threadIdx.x;
    const int c4 = tid & 31, mo = tid >> 5;
    const int cb = ct * 128 + c4 * 4;
    float s0 = 0, s1 = 0, s2 = 0, s3 = 0, q0 = 0, q1 = 0, q2 = 0, q3 = 0;
    for (int m = mc * 512 + mo; m < (mc + 1) * 512; m += 8) {
        const float4 v = *(const float4*)&y[(size_t)m * 1024 + cb];
        s0 += v.x; s1 += v.y; s2 += v.z; s3 += v.w;
        q0 = fmaf(v.x, v.x, q0); q1 = fmaf(v.y, v.y, q1);
        q2 = fmaf(v.z, v.z, q2); q3 = fmaf(v.w, v.w, q3);
    }
    __shared__ float rs[8][128];
    __shared__ float rq[8][128];
    rs[mo][c4 * 4 + 0] = s0; rs[mo][c4 * 4 + 1] = s1;
    rs[mo][c4 * 4 + 2] = s2; rs[mo][c4 * 4 + 3] = s3;
    rq[mo][c4 * 4 + 0] = q0; rq[mo][c4 * 4 + 1] = q1;
    rq[mo][c4 * 4 + 2] = q2; rq[mo][c4 * 4 + 3] = q3;
    __syncthreads();
    if (tid < 128) {
        float S = 0, Q = 0;
#pragma unroll
        for (int i = 0; i < 8; ++i) { S += rs[i][tid]; Q += rq[i][tid]; }
        float* p = &part[((size_t)mc * 1024 + ct * 128 + tid) * 2];
        p[0] = S; p[1] = Q;
    }
}

__global__ __launch_bounds__(256) void bn_final_k(
    const float* __restrict__ part, const float* __restrict__ gamma,
    const float* __restrict__ beta, float* __restrict__ scale,
    float* __restrict__ shift)
{
    const int c = blockIdx.x * 256 + threadIdx.x;
    if (c >= 1024) return;
    float S = 0, Q = 0;
    for (int mc = 0; mc < 32; ++mc) {
        S += part[((size_t)mc * 1024 + c) * 2 + 0];
        Q += part[((size_t)mc * 1024 + c) * 2 + 1];
    }
    const float inv = 1.f / 16384.f;
    const float mean = S * inv;
    const float var = Q * inv - mean * mean;
    const float sc = gamma[c] * rsqrtf(var + 1e-5f);
    scale[c] = sc;
    shift[c] = beta[c] - mean * sc;
}

__global__ __launch_bounds__(256) void bn_apply_k(
    const float* __restrict__ y, const float* __restrict__ scale,
    const float* __restrict__ shift, float* __restrict__ out)
{
    const int n4 = (16384 * 1024) / 4;
    const int stride = gridDim.x * blockDim.x;
    for (int i = blockIdx.x * blockDim.x + threadIdx.x; i < n4; i += stride) {
        const int c4 = i & 255;
        const float4 v = ((const float4*)y)[i];
        const float4 sc = ((const float4*)scale)[c4];
        const float4 sh = ((const float4*)shift)[c4];
        float4 o;
        o.x = fmaf(v.x, sc.x, sh.x);
        o.y = fmaf(v.y, sc.y, sh.y);
        o.z = fmaf(v.z, sc.z, sh.z);
        o.w = fmaf(v.w, sc.w, sh.w);
        ((float4*)out)[i] = o;
    }
}

// ---------------------------------------------------------------------------
extern "C" void kernel_launch(void* const* d_in, const int* in_sizes, int n_in,
                              void* d_out, int out_size, void* d_ws, size_t ws_size,
                              hipStream_t stream)
{
    (void)in_sizes; (void)n_in; (void)out_size; (void)ws_size;
    const float* x      = (const float*)d_in[0];
    const float* w_ih0  = (const float*)d_in[1];
    const float* w_hh0  = (const float*)d_in[2];
    const float* b_ih0  = (const float*)d_in[3];
    const float* b_hh0  = (const float*)d_in[4];
    const float* w_ih_r = (const float*)d_in[5];
    const float* w_hh_r = (const float*)d_in[6];
    const float* b_ih_r = (const float*)d_in[7];
    const float* b_hh_r = (const float*)d_in[8];
    const float* gamma  = (const float*)d_in[9];
    const float* beta   = (const float*)d_in[10];

    float* ws    = (float*)d_ws;
    float* xg    = ws;                      // 2*32*512*3*512 = 50,331,648 f
    float* y_raw = xg + (size_t)50331648;   // 16,777,216 f
    float* hglob = y_raw + 16777216;        // 65,536 f
    float* part  = hglob + 65536;           // 65,536 f
    float* scale = part + 65536;            // 1,024 f
    float* shift = scale + 1024;            // 1,024 f
    int* flags   = (int*)(shift + 1024);    // 3*2*4*32*512 = 393,216 i
    // total ws use: ~258 MB

    hipMemsetAsync(flags, 0, (size_t)3 * 2 * 4 * 32 * 512 * sizeof(int), stream);

    for (int l = 0; l < 3; ++l) {
        const int K = (l == 0) ? 1280 : 1024;
        const float* Ain = (l == 0) ? x : y_raw;
        const float* sc_in = (l == 0) ? nullptr : scale;   // BN of prev layer
        const float* sh_in = (l == 0) ? nullptr : shift;
        const float* wih = (l == 0) ? w_ih0 : (w_ih_r + (size_t)(l - 1) * 2 * 1536 * 1024);
        const float* bih = (l == 0) ? b_ih0 : (b_ih_r + (size_t)(l - 1) * 2 * 1536);
        const float* whh = (l == 0) ? w_hh0 : (w_hh_r + (size_t)(l - 1) * 2 * 1536 * 512);
        const float* bhh = (l == 0) ? b_hh0 : (b_hh_r + (size_t)(l - 1) * 2 * 1536);

        gemm_xg<<<dim3(128, 24), 256, 0, stream>>>(Ain, wih, bih, sc_in, sh_in, xg, K);
        scan_gru<<<256, 256, 0, stream>>>(xg, whh, bhh, hglob,
                                          flags + (size_t)l * 2 * 4 * 32 * 512, y_raw);
        bn_stats_k<<<dim3(8, 32), 256, 0, stream>>>(y_raw, part);
        bn_final_k<<<4, 256, 0, stream>>>(part, gamma + l * 1024, beta + l * 1024,
                                          scale, shift);
        if (l == 2)
            bn_apply_k<<<2048, 256, 0, stream>>>(y_raw, scale, shift, (float*)d_out);
    }
}

// Round 6
// 20461.382 us; speedup vs baseline: 1.0191x; 1.0191x over previous
//
#include <hip/hip_runtime.h>
#include <cstdint>
#include <cstddef>

// Problem constants
#define BB 32
#define TT 512
#define FF 1280
#define HH 512
// derived: M = BB*TT = 16384, N = 3072 (2 dirs * 3 gates * 512), C = 1024

static __device__ __forceinline__ float sigm(float x) {
    x = fminf(30.f, fmaxf(-30.f, x));
    return 1.f / (1.f + __expf(-x));
}
static __device__ __forceinline__ float tanh_fast(float x) {
    x = fminf(15.f, fmaxf(-15.f, x));
    const float e = __expf(2.f * x);
    return (e - 1.f) / (e + 1.f);
}

// ---------------------------------------------------------------------------
// GEMM: xg[d][b][t][g][j] = sum_k A'[m][k] * W[n][k] + bias[n]
//   A' = A (layer 0) or BN(A) = A*bn_scale[k]+bn_shift[k] fused at load.
//   A: [16384][K] row-major, W: [3072][K] row-major (dir-major),
//   m = b*512 + t, n = d*1536 + g*512 + j
// 128x128 block tile, BK=16, 256 threads, 8x8 acc/thread.
// ---------------------------------------------------------------------------
__global__ __launch_bounds__(256, 2) void gemm_xg(
    const float* __restrict__ A, const float* __restrict__ W,
    const float* __restrict__ bias, const float* __restrict__ bn_scale,
    const float* __restrict__ bn_shift, float* __restrict__ xg, int K)
{
    __shared__ float As[16][132];
    __shared__ float Ws[16][132];
    const int tid = threadIdx.x;
    const int tx = tid & 15, ty = tid >> 4;
    const int m0 = blockIdx.x * 128, n0 = blockIdx.y * 128;

    float acc[8][8];
#pragma unroll
    for (int i = 0; i < 8; ++i)
#pragma unroll
        for (int j = 0; j < 8; ++j) acc[i][j] = 0.f;

    const int sr = tid >> 2;       // 0..63 (row within half-tile)
    const int sk = (tid & 3) * 4;  // 0,4,8,12 (k offset)

    for (int k0 = 0; k0 < K; k0 += 16) {
        float4 sc4, sh4;
        if (bn_scale) {
            sc4 = *(const float4*)&bn_scale[k0 + sk];
            sh4 = *(const float4*)&bn_shift[k0 + sk];
        }
#pragma unroll
        for (int it = 0; it < 2; ++it) {
            const int r = sr + it * 64;
            float4 a = *(const float4*)&A[(size_t)(m0 + r) * K + k0 + sk];
            if (bn_scale) {
                a.x = fmaf(a.x, sc4.x, sh4.x);
                a.y = fmaf(a.y, sc4.y, sh4.y);
                a.z = fmaf(a.z, sc4.z, sh4.z);
                a.w = fmaf(a.w, sc4.w, sh4.w);
            }
            As[sk + 0][r] = a.x; As[sk + 1][r] = a.y;
            As[sk + 2][r] = a.z; As[sk + 3][r] = a.w;
            const float4 w = *(const float4*)&W[(size_t)(n0 + r) * K + k0 + sk];
            Ws[sk + 0][r] = w.x; Ws[sk + 1][r] = w.y;
            Ws[sk + 2][r] = w.z; Ws[sk + 3][r] = w.w;
        }
        __syncthreads();
#pragma unroll
        for (int k = 0; k < 16; ++k) {
            const float4 a0 = *(const float4*)&As[k][ty * 4];
            const float4 a1 = *(const float4*)&As[k][64 + ty * 4];
            const float4 b0 = *(const float4*)&Ws[k][tx * 4];
            const float4 b1 = *(const float4*)&Ws[k][64 + tx * 4];
            const float ar[8] = {a0.x, a0.y, a0.z, a0.w, a1.x, a1.y, a1.z, a1.w};
            const float br[8] = {b0.x, b0.y, b0.z, b0.w, b1.x, b1.y, b1.z, b1.w};
#pragma unroll
            for (int i = 0; i < 8; ++i)
#pragma unroll
                for (int j = 0; j < 8; ++j)
                    acc[i][j] = fmaf(ar[i], br[j], acc[i][j]);
        }
        __syncthreads();
    }

    // Epilogue: n-tile never spans dir/gate boundaries (128 | 512).
    const int d = n0 / 1536;
    const int rem0 = n0 - d * 1536;
    const int g = rem0 >> 9;
    const int jj0 = rem0 & 511;
    const int b = m0 >> 9;       // m-tile never spans batch boundary (128 | 512)
    const int t0 = m0 & 511;
    const size_t base_db = (size_t)(d * 32 + b) * 786432 + (size_t)g * 512;

    float4 bias4[2];
#pragma unroll
    for (int ch = 0; ch < 2; ++ch)
        bias4[ch] = *(const float4*)&bias[d * 1536 + g * 512 + jj0 + ch * 64 + tx * 4];

#pragma unroll
    for (int ri = 0; ri < 8; ++ri) {
        const int t = t0 + (ri >> 2) * 64 + ty * 4 + (ri & 3);
        const size_t rowb = base_db + (size_t)t * 1536;
#pragma unroll
        for (int ch = 0; ch < 2; ++ch) {
            float4 v;
            v.x = acc[ri][ch * 4 + 0] + bias4[ch].x;
            v.y = acc[ri][ch * 4 + 1] + bias4[ch].y;
            v.z = acc[ri][ch * 4 + 2] + bias4[ch].z;
            v.w = acc[ri][ch * 4 + 3] + bias4[ch].w;
            *(float4*)&xg[rowb + (size_t)(jj0 + ch * 64 + tx * 4)] = v;
        }
    }
}

// ---------------------------------------------------------------------------
// Recurrent scan. Grid = 256 blocks x 256 threads (1 block/CU via ~119KB LDS;
// all blocks co-resident). Block (dir, bg, jb) owns batches [bg*8, +8),
// h-columns [jb*16, +16). w_hh slice (96KB) resident in LDS for all 512 steps.
//
// Sync protocol (asymmetric, r5 post-mortem):
//  PRODUCER (proven in r2): normal cached h stores -> __syncthreads (each
//    wave drains its own vmcnt before s_barrier) -> tid0: release fence
//    (s_waitcnt + buffer_wbl2: flushes dirty L2 to coherence point) ->
//    relaxed flag store. Flag=1 => h globally visible.
//  CONSUMER (fence-free, provably ordered): relaxed flag spin (NO buffer_inv,
//    unlike r2 which inv'd per poll iteration!) -> barrier -> h loads as
//    relaxed agent-scope atomics (sc0 sc1: bypass L1/L2, read the coherence
//    point). In-order issue guarantees they execute after the spin exits.
//    All other post-spin reads (xg/bhh) are immutable within this kernel.
// h double-buffered by step parity. y stores nontemporal (keep L2 clean so
// the per-step wbl2 has little to write back).
// ---------------------------------------------------------------------------
__global__ __launch_bounds__(256, 1) void scan_gru(
    const float* __restrict__ xg,   // [2][32][512][3][512]
    const float* __restrict__ whh,  // [2][1536][512]
    const float* __restrict__ bhh,  // [2][1536]
    float* __restrict__ hglob,      // [2 parity][2 dir][4 bg][128][8][4]
    int* flags,                     // [2 dir][4 bg][32 jb][512 t]
    float* __restrict__ y)          // [16384][1024]
{
    __shared__ float w_lds[3][128][16][4];  // 96KB: [g][k4][jj][kk]
    __shared__ float h_lds[128][8][4];      // 16KB: [k4][b][kk]
    __shared__ float parts[4][8][8][7];     // 7KB:  [kq][b][jgrp][g*2+js], pad 6->7

    const int bid = blockIdx.x;
    const int dir = bid >> 7;
    const int bg = (bid >> 5) & 3;
    const int jb = bid & 31;
    const int tid = threadIdx.x;

    // Stage this block's w_hh rows {j, 512+j, 1024+j} for j in [jb*16, +16)
    for (int r = 0; r < 48; ++r) {
        const int g = r >> 4, jj = r & 15;
        const float* row = whh + ((size_t)dir * 1536 + g * 512 + jb * 16 + jj) * 512;
#pragma unroll
        for (int p = 0; p < 2; ++p) {
            const int k = p * 256 + tid;
            w_lds[g][k >> 2][jj][k & 3] = row[k];
        }
    }

    // compute-phase mapping (all 256 threads)
    const int cb = tid & 7;           // batch-local
    const int jgrp = (tid >> 3) & 7;  // owns 2 j-columns
    const int kq = tid >> 6;          // k quarter
    const int jj0 = jgrp * 2;
    // reduce-phase mapping (tid < 128)
    const int rjl = tid & 15, rb = tid >> 4;
    const int jglob = jb * 16 + rjl;

    float br_ = 0.f, bz_ = 0.f, bn_ = 0.f;
    if (tid < 128) {
        br_ = bhh[dir * 1536 + 0 * 512 + jglob];
        bz_ = bhh[dir * 1536 + 1 * 512 + jglob];
        bn_ = bhh[dir * 1536 + 2 * 512 + jglob];
    }
    const int flag_base = (dir * 4 + bg) * 32 * 512;
    __syncthreads();

    for (int t = 0; t < TT; ++t) {
        const int tt = (dir == 0) ? t : (TT - 1 - t);

        // prefetch xg for this step (issued before the spin; normal cached loads)
        float xr = 0.f, xz = 0.f, xn = 0.f;
        if (tid < 128) {
            const size_t mb = (((size_t)dir * 32 + bg * 8 + rb) * 512 + tt) * 1536;
            xr = xg[mb + 0 * 512 + jglob];
            xz = xg[mb + 1 * 512 + jglob];
            xn = xg[mb + 2 * 512 + jglob];
        }

        if (t > 0) {
            if (tid < 32) {
                int* fp = flags + flag_base + tid * 512 + (t - 1);
                while (__hip_atomic_load(fp, __ATOMIC_RELAXED,
                                         __HIP_MEMORY_SCOPE_AGENT) == 0)
                    __builtin_amdgcn_s_sleep(2);
            }
            __syncthreads();
            // stage h(t-1): 16KB, parity (t-1)&1, via coherence-point (sc1)
            // loads. Regs first so 16 loads pipeline, then spill to LDS.
            const float* src = hglob +
                (size_t)((((t & 1) ^ 1) * 2 + dir) * 4 + bg) * 4096;
            float tmp[16];
#pragma unroll
            for (int i = 0; i < 16; ++i)
                tmp[i] = __hip_atomic_load(&src[i * 256 + tid], __ATOMIC_RELAXED,
                                           __HIP_MEMORY_SCOPE_AGENT);
            float* dstf = (float*)h_lds;
#pragma unroll
            for (int i = 0; i < 16; ++i) dstf[i * 256 + tid] = tmp[i];
            __syncthreads();
        } else {
            float4* dst = (float4*)h_lds;
            const float4 z4 = make_float4(0.f, 0.f, 0.f, 0.f);
#pragma unroll
            for (int i = 0; i < 4; ++i) dst[i * 256 + tid] = z4;
            __syncthreads();
        }

        // partial dot products over this thread's k-quarter
        float p00 = 0, p01 = 0, p10 = 0, p11 = 0, p20 = 0, p21 = 0;
#pragma unroll 4
        for (int k4 = 0; k4 < 32; ++k4) {
            const int kk = kq * 32 + k4;
            const float4 h4 = *(const float4*)&h_lds[kk][cb][0];
            const float4 w0a = *(const float4*)&w_lds[0][kk][jj0][0];
            const float4 w0b = *(const float4*)&w_lds[0][kk][jj0 + 1][0];
            const float4 w1a = *(const float4*)&w_lds[1][kk][jj0][0];
            const float4 w1b = *(const float4*)&w_lds[1][kk][jj0 + 1][0];
            const float4 w2a = *(const float4*)&w_lds[2][kk][jj0][0];
            const float4 w2b = *(const float4*)&w_lds[2][kk][jj0 + 1][0];
            p00 = fmaf(h4.x, w0a.x, p00); p00 = fmaf(h4.y, w0a.y, p00);
            p00 = fmaf(h4.z, w0a.z, p00); p00 = fmaf(h4.w, w0a.w, p00);
            p01 = fmaf(h4.x, w0b.x, p01); p01 = fmaf(h4.y, w0b.y, p01);
            p01 = fmaf(h4.z, w0b.z, p01); p01 = fmaf(h4.w, w0b.w, p01);
            p10 = fmaf(h4.x, w1a.x, p10); p10 = fmaf(h4.y, w1a.y, p10);
            p10 = fmaf(h4.z, w1a.z, p10); p10 = fmaf(h4.w, w1a.w, p10);
            p11 = fmaf(h4.x, w1b.x, p11); p11 = fmaf(h4.y, w1b.y, p11);
            p11 = fmaf(h4.z, w1b.z, p11); p11 = fmaf(h4.w, w1b.w, p11);
            p20 = fmaf(h4.x, w2a.x, p20); p20 = fmaf(h4.y, w2a.y, p20);
            p20 = fmaf(h4.z, w2a.z, p20); p20 = fmaf(h4.w, w2a.w, p20);
            p21 = fmaf(h4.x, w2b.x, p21); p21 = fmaf(h4.y, w2b.y, p21);
            p21 = fmaf(h4.z, w2b.z, p21); p21 = fmaf(h4.w, w2b.w, p21);
        }
        {
            float* pp = &parts[kq][cb][jgrp][0];
            pp[0] = p00; pp[1] = p01; pp[2] = p10;
            pp[3] = p11; pp[4] = p20; pp[5] = p21;
        }
        __syncthreads();

        if (tid < 128) {
            const int jgr = rjl >> 1, js = rjl & 1;
            float gr = br_, gz = bz_, gn = bn_;
#pragma unroll
            for (int q = 0; q < 4; ++q) {
                gr += parts[q][rb][jgr][0 + js];
                gz += parts[q][rb][jgr][2 + js];
                gn += parts[q][rb][jgr][4 + js];
            }
            const float hold = h_lds[jglob >> 2][rb][jglob & 3];
            const float r = sigm(xr + gr);
            const float z = sigm(xz + gz);
            const float nn = tanh_fast(xn + r * gn);
            const float hnew = (1.f - z) * nn + z * hold;
            // y[m][c], m = b*512 + tt, c = dir*512 + j — nontemporal store
            // (write-around: keeps L2 clean so the per-step wbl2 is cheap)
            __builtin_nontemporal_store(
                hnew, &y[((size_t)(bg * 8 + rb) * 512 + tt) * 1024 +
                         dir * 512 + jglob]);
            // h slice, parity t&1 — NORMAL cached store; published by the
            // release fence below (proven r2 producer edge).
            hglob[(size_t)(((t & 1) * 2 + dir) * 4 + bg) * 4096 +
                  (size_t)(jglob >> 2) * 32 + rb * 4 + (jglob & 3)] = hnew;
        }
        __syncthreads();   // each wave drains its own vmcnt before s_barrier
        if (tid == 0) {
            // release: s_waitcnt + buffer_wbl2 -> h stores at coherence point
            __builtin_amdgcn_fence(__ATOMIC_RELEASE, "agent");
            __hip_atomic_store(flags + flag_base + jb * 512 + t, 1,
                               __ATOMIC_RELAXED, __HIP_MEMORY_SCOPE_AGENT);
        }
    }
}

// ---------------------------------------------------------------------------
// BatchNorm: partial sums -> finalize (scale/shift). Apply is fused into the
// next layer's GEMM A-load; only the final layer uses bn_apply_k -> d_out.
// ---------------------------------------------------------------------------
__global__ __launch_bounds__(256) void bn_stats_k(
    const float* __restrict__ y, float* __restrict__ part)
{
    const int ct = blockIdx.x;  // 0..7  (c tile of 128)
    const int mc = blockIdx.y;  // 0..31 (m chunk of 512)
    const int tid = threadIdx.x;
    const int c4 = tid & 31, mo = tid >> 5;
    const int cb = ct * 128 + c4 * 4;
    float s0 = 0, s1 = 0, s2 = 0, s3 = 0, q0 = 0, q1 = 0, q2 = 0, q3 = 0;
    for (int m = mc * 512 + mo; m < (mc + 1) * 512; m += 8) {
        const float4 v = *(const float4*)&y[(size_t)m * 1024 + cb];
        s0 += v.x; s1 += v.y; s2 += v.z; s3 += v.w;
        q0 = fmaf(v.x, v.x, q0); q1 = fmaf(v.y, v.y, q1);
        q2 = fmaf(v.z, v.z, q2); q3 = fmaf(v.w, v.w, q3);
    }
    __shared__ float rs[8][128];
    __shared__ float rq[8][128];
    rs[mo][c4 * 4 + 0] = s0; rs[mo][c4 * 4 + 1] = s1;
    rs[mo][c4 * 4 + 2] = s2; rs[mo][c4 * 4 + 3] = s3;
    rq[mo][c4 * 4 + 0] = q0; rq[mo][c4 * 4 + 1] = q1;
    rq[mo][c4 * 4 + 2] = q2; rq[mo][c4 * 4 + 3] = q3;
    __syncthreads();
    if (tid < 128) {
        float S = 0, Q = 0;
#pragma unroll
        for (int i = 0; i < 8; ++i) { S += rs[i][tid]; Q += rq[i][tid]; }
        float* p = &part[((size_t)mc * 1024 + ct * 128 + tid) * 2];
        p[0] = S; p[1] = Q;
    }
}

__global__ __launch_bounds__(256) void bn_final_k(
    const float* __restrict__ part, const float* __restrict__ gamma,
    const float* __restrict__ beta, float* __restrict__ scale,
    float* __restrict__ shift)
{
    const int c = blockIdx.x * 256 + threadIdx.x;
    if (c >= 1024) return;
    float S = 0, Q = 0;
    for (int mc = 0; mc < 32; ++mc) {
        S += part[((size_t)mc * 1024 + c) * 2 + 0];
        Q += part[((size_t)mc * 1024 + c) * 2 + 1];
    }
    const float inv = 1.f / 16384.f;
    const float mean = S * inv;
    const float var = Q * inv - mean * mean;
    const float sc = gamma[c] * rsqrtf(var + 1e-5f);
    scale[c] = sc;
    shift[c] = beta[c] - mean * sc;
}

__global__ __launch_bounds__(256) void bn_apply_k(
    const float* __restrict__ y, const float* __restrict__ scale,
    const float* __restrict__ shift, float* __restrict__ out)
{
    const int n4 = (16384 * 1024) / 4;
    const int stride = gridDim.x * blockDim.x;
    for (int i = blockIdx.x * blockDim.x + threadIdx.x; i < n4; i += stride) {
        const int c4 = i & 255;
        const float4 v = ((const float4*)y)[i];
        const float4 sc = ((const float4*)scale)[c4];
        const float4 sh = ((const float4*)shift)[c4];
        float4 o;
        o.x = fmaf(v.x, sc.x, sh.x);
        o.y = fmaf(v.y, sc.y, sh.y);
        o.z = fmaf(v.z, sc.z, sh.z);
        o.w = fmaf(v.w, sc.w, sh.w);
        ((float4*)out)[i] = o;
    }
}

// ---------------------------------------------------------------------------
extern "C" void kernel_launch(void* const* d_in, const int* in_sizes, int n_in,
                              void* d_out, int out_size, void* d_ws, size_t ws_size,
                              hipStream_t stream)
{
    (void)in_sizes; (void)n_in; (void)out_size; (void)ws_size;
    const float* x      = (const float*)d_in[0];
    const float* w_ih0  = (const float*)d_in[1];
    const float* w_hh0  = (const float*)d_in[2];
    const float* b_ih0  = (const float*)d_in[3];
    const float* b_hh0  = (const float*)d_in[4];
    const float* w_ih_r = (const float*)d_in[5];
    const float* w_hh_r = (const float*)d_in[6];
    const float* b_ih_r = (const float*)d_in[7];
    const float* b_hh_r = (const float*)d_in[8];
    const float* gamma  = (const float*)d_in[9];
    const float* beta   = (const float*)d_in[10];

    float* ws    = (float*)d_ws;
    float* xg    = ws;                      // 2*32*512*3*512 = 50,331,648 f
    float* y_raw = xg + (size_t)50331648;   // 16,777,216 f
    float* hglob = y_raw + 16777216;        // 65,536 f
    float* part  = hglob + 65536;           // 65,536 f
    float* scale = part + 65536;            // 1,024 f
    float* shift = scale + 1024;            // 1,024 f
    int* flags   = (int*)(shift + 1024);    // 3*2*4*32*512 = 393,216 i
    // total ws use: ~258 MB

    hipMemsetAsync(flags, 0, (size_t)3 * 2 * 4 * 32 * 512 * sizeof(int), stream);

    for (int l = 0; l < 3; ++l) {
        const int K = (l == 0) ? 1280 : 1024;
        const float* Ain = (l == 0) ? x : y_raw;
        const float* sc_in = (l == 0) ? nullptr : scale;   // BN of prev layer
        const float* sh_in = (l == 0) ? nullptr : shift;
        const float* wih = (l == 0) ? w_ih0 : (w_ih_r + (size_t)(l - 1) * 2 * 1536 * 1024);
        const float* bih = (l == 0) ? b_ih0 : (b_ih_r + (size_t)(l - 1) * 2 * 1536);
        const float* whh = (l == 0) ? w_hh0 : (w_hh_r + (size_t)(l - 1) * 2 * 1536 * 512);
        const float* bhh = (l == 0) ? b_hh0 : (b_hh_r + (size_t)(l - 1) * 2 * 1536);

        gemm_xg<<<dim3(128, 24), 256, 0, stream>>>(Ain, wih, bih, sc_in, sh_in, xg, K);
        scan_gru<<<256, 256, 0, stream>>>(xg, whh, bhh, hglob,
                                          flags + (size_t)l * 2 * 4 * 32 * 512, y_raw);
        bn_stats_k<<<dim3(8, 32), 256, 0, stream>>>(y_raw, part);
        bn_final_k<<<4, 256, 0, stream>>>(part, gamma + l * 1024, beta + l * 1024,
                                          scale, shift);
        if (l == 2)
            bn_apply_k<<<2048, 256, 0, stream>>>(y_raw, scale, shift, (float*)d_out);
    }
}

// Round 8
// 11998.863 us; speedup vs baseline: 1.7378x; 1.7053x over previous
//
#include <hip/hip_runtime.h>
#include <cstdint>
#include <cstddef>

// Problem constants
#define BB 32
#define TT 512
#define FF 1280
#define HH 512
// derived: M = BB*TT = 16384, N = 3072 (2 dirs * 3 gates * 512), C = 1024

static __device__ __forceinline__ float sigm(float x) {
    x = fminf(30.f, fmaxf(-30.f, x));
    return 1.f / (1.f + __expf(-x));
}
static __device__ __forceinline__ float tanh_fast(float x) {
    x = fminf(15.f, fmaxf(-15.f, x));
    const float e = __expf(2.f * x);
    return (e - 1.f) / (e + 1.f);
}

// ---------------------------------------------------------------------------
// GEMM: xg[d][b][t][g][j] = sum_k A'[m][k] * W[n][k] + bias[n]
//   A' = A (layer 0) or BN(A) = A*bn_scale[k]+bn_shift[k] fused at load.
//   A: [16384][K] row-major, W: [3072][K] row-major (dir-major),
//   m = b*512 + t, n = d*1536 + g*512 + j
// 128x128 block tile, BK=16, 256 threads, 8x8 acc/thread.
// ---------------------------------------------------------------------------
__global__ __launch_bounds__(256, 2) void gemm_xg(
    const float* __restrict__ A, const float* __restrict__ W,
    const float* __restrict__ bias, const float* __restrict__ bn_scale,
    const float* __restrict__ bn_shift, float* __restrict__ xg, int K)
{
    __shared__ float As[16][132];
    __shared__ float Ws[16][132];
    const int tid = threadIdx.x;
    const int tx = tid & 15, ty = tid >> 4;
    const int m0 = blockIdx.x * 128, n0 = blockIdx.y * 128;

    float acc[8][8];
#pragma unroll
    for (int i = 0; i < 8; ++i)
#pragma unroll
        for (int j = 0; j < 8; ++j) acc[i][j] = 0.f;

    const int sr = tid >> 2;       // 0..63 (row within half-tile)
    const int sk = (tid & 3) * 4;  // 0,4,8,12 (k offset)

    for (int k0 = 0; k0 < K; k0 += 16) {
        float4 sc4, sh4;
        if (bn_scale) {
            sc4 = *(const float4*)&bn_scale[k0 + sk];
            sh4 = *(const float4*)&bn_shift[k0 + sk];
        }
#pragma unroll
        for (int it = 0; it < 2; ++it) {
            const int r = sr + it * 64;
            float4 a = *(const float4*)&A[(size_t)(m0 + r) * K + k0 + sk];
            if (bn_scale) {
                a.x = fmaf(a.x, sc4.x, sh4.x);
                a.y = fmaf(a.y, sc4.y, sh4.y);
                a.z = fmaf(a.z, sc4.z, sh4.z);
                a.w = fmaf(a.w, sc4.w, sh4.w);
            }
            As[sk + 0][r] = a.x; As[sk + 1][r] = a.y;
            As[sk + 2][r] = a.z; As[sk + 3][r] = a.w;
            const float4 w = *(const float4*)&W[(size_t)(n0 + r) * K + k0 + sk];
            Ws[sk + 0][r] = w.x; Ws[sk + 1][r] = w.y;
            Ws[sk + 2][r] = w.z; Ws[sk + 3][r] = w.w;
        }
        __syncthreads();
#pragma unroll
        for (int k = 0; k < 16; ++k) {
            const float4 a0 = *(const float4*)&As[k][ty * 4];
            const float4 a1 = *(const float4*)&As[k][64 + ty * 4];
            const float4 b0 = *(const float4*)&Ws[k][tx * 4];
            const float4 b1 = *(const float4*)&Ws[k][64 + tx * 4];
            const float ar[8] = {a0.x, a0.y, a0.z, a0.w, a1.x, a1.y, a1.z, a1.w};
            const float br[8] = {b0.x, b0.y, b0.z, b0.w, b1.x, b1.y, b1.z, b1.w};
#pragma unroll
            for (int i = 0; i < 8; ++i)
#pragma unroll
                for (int j = 0; j < 8; ++j)
                    acc[i][j] = fmaf(ar[i], br[j], acc[i][j]);
        }
        __syncthreads();
    }

    // Epilogue: n-tile never spans dir/gate boundaries (128 | 512).
    const int d = n0 / 1536;
    const int rem0 = n0 - d * 1536;
    const int g = rem0 >> 9;
    const int jj0 = rem0 & 511;
    const int b = m0 >> 9;       // m-tile never spans batch boundary (128 | 512)
    const int t0 = m0 & 511;
    const size_t base_db = (size_t)(d * 32 + b) * 786432 + (size_t)g * 512;

    float4 bias4[2];
#pragma unroll
    for (int ch = 0; ch < 2; ++ch)
        bias4[ch] = *(const float4*)&bias[d * 1536 + g * 512 + jj0 + ch * 64 + tx * 4];

#pragma unroll
    for (int ri = 0; ri < 8; ++ri) {
        const int t = t0 + (ri >> 2) * 64 + ty * 4 + (ri & 3);
        const size_t rowb = base_db + (size_t)t * 1536;
#pragma unroll
        for (int ch = 0; ch < 2; ++ch) {
            float4 v;
            v.x = acc[ri][ch * 4 + 0] + bias4[ch].x;
            v.y = acc[ri][ch * 4 + 1] + bias4[ch].y;
            v.z = acc[ri][ch * 4 + 2] + bias4[ch].z;
            v.w = acc[ri][ch * 4 + 3] + bias4[ch].w;
            *(float4*)&xg[rowb + (size_t)(jj0 + ch * 64 + tx * 4)] = v;
        }
    }
}

// ---------------------------------------------------------------------------
// Recurrent scan. Grid = 256 blocks x 256 threads (1 block/CU via ~119KB LDS;
// all blocks co-resident). Block (dir, bg, jb) owns batches [bg*8, +8),
// h-columns [jb*16, +16). w_hh slice (96KB) resident in LDS for all 512 steps.
//
// Sync protocol (r6 post-mortem: NO cache-maintenance ops at all):
//  PRODUCER: each of the 128 result lanes publishes its 1 h-float via
//    agent-scope atomicExch WITH USED RETURN (global_atomic_swap sc0 sc1:
//    executes at the coherence point; the returned old value cannot arrive
//    before the RMW completed at L3, so vmcnt-ack => globally visible).
//    __syncthreads (each wave: s_waitcnt vmcnt(0) before s_barrier) => ALL
//    lanes' swaps acked -> tid0 stores the flag (relaxed sc1). This replaces
//    r2/r6's per-step buffer_wbl2 full-L2 writeback walk, and fixes r5's bug
//    (vmcnt-ack of a plain sc1 STORE does not imply coherence-point arrival;
//    the flag overtook in-flight h stores).
//  CONSUMER (r6, proven): relaxed flag spin (no buffer_inv) -> barrier ->
//    h loads as relaxed agent-scope sc1 atomics (bypass stale L1/L2, read
//    the coherence point), pipelined 16-deep through registers.
// h double-buffered by step parity (flag protocol bounds group skew to 1).
// y stores nontemporal (write-around, keep L2 clean).
// ---------------------------------------------------------------------------
__global__ __launch_bounds__(256, 1) void scan_gru(
    const float* __restrict__ xg,   // [2][32][512][3][512]
    const float* __restrict__ whh,  // [2][1536][512]
    const float* __restrict__ bhh,  // [2][1536]
    float* __restrict__ hglob,      // [2 parity][2 dir][4 bg][128][8][4]
    int* flags,                     // [2 dir][4 bg][32 jb][512 t]
    float* __restrict__ y)          // [16384][1024]
{
    __shared__ float w_lds[3][128][16][4];  // 96KB: [g][k4][jj][kk]
    __shared__ float h_lds[128][8][4];      // 16KB: [k4][b][kk]
    __shared__ float parts[4][8][8][7];     // 7KB:  [kq][b][jgrp][g*2+js], pad 6->7

    const int bid = blockIdx.x;
    const int dir = bid >> 7;
    const int bg = (bid >> 5) & 3;
    const int jb = bid & 31;
    const int tid = threadIdx.x;

    // Stage this block's w_hh rows {j, 512+j, 1024+j} for j in [jb*16, +16)
    for (int r = 0; r < 48; ++r) {
        const int g = r >> 4, jj = r & 15;
        const float* row = whh + ((size_t)dir * 1536 + g * 512 + jb * 16 + jj) * 512;
#pragma unroll
        for (int p = 0; p < 2; ++p) {
            const int k = p * 256 + tid;
            w_lds[g][k >> 2][jj][k & 3] = row[k];
        }
    }

    // compute-phase mapping (all 256 threads)
    const int cb = tid & 7;           // batch-local
    const int jgrp = (tid >> 3) & 7;  // owns 2 j-columns
    const int kq = tid >> 6;          // k quarter
    const int jj0 = jgrp * 2;
    // reduce-phase mapping (tid < 128)
    const int rjl = tid & 15, rb = tid >> 4;
    const int jglob = jb * 16 + rjl;

    float br_ = 0.f, bz_ = 0.f, bn_ = 0.f;
    if (tid < 128) {
        br_ = bhh[dir * 1536 + 0 * 512 + jglob];
        bz_ = bhh[dir * 1536 + 1 * 512 + jglob];
        bn_ = bhh[dir * 1536 + 2 * 512 + jglob];
    }
    const int flag_base = (dir * 4 + bg) * 32 * 512;
    __syncthreads();

    for (int t = 0; t < TT; ++t) {
        const int tt = (dir == 0) ? t : (TT - 1 - t);

        // prefetch xg for this step (issued before the spin; normal cached loads)
        float xr = 0.f, xz = 0.f, xn = 0.f;
        if (tid < 128) {
            const size_t mb = (((size_t)dir * 32 + bg * 8 + rb) * 512 + tt) * 1536;
            xr = xg[mb + 0 * 512 + jglob];
            xz = xg[mb + 1 * 512 + jglob];
            xn = xg[mb + 2 * 512 + jglob];
        }

        if (t > 0) {
            if (tid < 32) {
                int* fp = flags + flag_base + tid * 512 + (t - 1);
                while (__hip_atomic_load(fp, __ATOMIC_RELAXED,
                                         __HIP_MEMORY_SCOPE_AGENT) == 0)
                    __builtin_amdgcn_s_sleep(2);
            }
            __syncthreads();
            // stage h(t-1): 16KB, parity (t-1)&1, via coherence-point (sc1)
            // loads. Regs first so 16 loads pipeline, then spill to LDS.
            const float* src = hglob +
                (size_t)((((t & 1) ^ 1) * 2 + dir) * 4 + bg) * 4096;
            float tmp[16];
#pragma unroll
            for (int i = 0; i < 16; ++i)
                tmp[i] = __hip_atomic_load(&src[i * 256 + tid], __ATOMIC_RELAXED,
                                           __HIP_MEMORY_SCOPE_AGENT);
            float* dstf = (float*)h_lds;
#pragma unroll
            for (int i = 0; i < 16; ++i) dstf[i * 256 + tid] = tmp[i];
            __syncthreads();
        } else {
            float4* dst = (float4*)h_lds;
            const float4 z4 = make_float4(0.f, 0.f, 0.f, 0.f);
#pragma unroll
            for (int i = 0; i < 4; ++i) dst[i * 256 + tid] = z4;
            __syncthreads();
        }

        // partial dot products over this thread's k-quarter
        float p00 = 0, p01 = 0, p10 = 0, p11 = 0, p20 = 0, p21 = 0;
#pragma unroll 4
        for (int k4 = 0; k4 < 32; ++k4) {
            const int kk = kq * 32 + k4;
            const float4 h4 = *(const float4*)&h_lds[kk][cb][0];
            const float4 w0a = *(const float4*)&w_lds[0][kk][jj0][0];
            const float4 w0b = *(const float4*)&w_lds[0][kk][jj0 + 1][0];
            const float4 w1a = *(const float4*)&w_lds[1][kk][jj0][0];
            const float4 w1b = *(const float4*)&w_lds[1][kk][jj0 + 1][0];
            const float4 w2a = *(const float4*)&w_lds[2][kk][jj0][0];
            const float4 w2b = *(const float4*)&w_lds[2][kk][jj0 + 1][0];
            p00 = fmaf(h4.x, w0a.x, p00); p00 = fmaf(h4.y, w0a.y, p00);
            p00 = fmaf(h4.z, w0a.z, p00); p00 = fmaf(h4.w, w0a.w, p00);
            p01 = fmaf(h4.x, w0b.x, p01); p01 = fmaf(h4.y, w0b.y, p01);
            p01 = fmaf(h4.z, w0b.z, p01); p01 = fmaf(h4.w, w0b.w, p01);
            p10 = fmaf(h4.x, w1a.x, p10); p10 = fmaf(h4.y, w1a.y, p10);
            p10 = fmaf(h4.z, w1a.z, p10); p10 = fmaf(h4.w, w1a.w, p10);
            p11 = fmaf(h4.x, w1b.x, p11); p11 = fmaf(h4.y, w1b.y, p11);
            p11 = fmaf(h4.z, w1b.z, p11); p11 = fmaf(h4.w, w1b.w, p11);
            p20 = fmaf(h4.x, w2a.x, p20); p20 = fmaf(h4.y, w2a.y, p20);
            p20 = fmaf(h4.z, w2a.z, p20); p20 = fmaf(h4.w, w2a.w, p20);
            p21 = fmaf(h4.x, w2b.x, p21); p21 = fmaf(h4.y, w2b.y, p21);
            p21 = fmaf(h4.z, w2b.z, p21); p21 = fmaf(h4.w, w2b.w, p21);
        }
        {
            float* pp = &parts[kq][cb][jgrp][0];
            pp[0] = p00; pp[1] = p01; pp[2] = p10;
            pp[3] = p11; pp[4] = p20; pp[5] = p21;
        }
        __syncthreads();

        if (tid < 128) {
            const int jgr = rjl >> 1, js = rjl & 1;
            float gr = br_, gz = bz_, gn = bn_;
#pragma unroll
            for (int q = 0; q < 4; ++q) {
                gr += parts[q][rb][jgr][0 + js];
                gz += parts[q][rb][jgr][2 + js];
                gn += parts[q][rb][jgr][4 + js];
            }
            const float hold = h_lds[jglob >> 2][rb][jglob & 3];
            const float r = sigm(xr + gr);
            const float z = sigm(xz + gz);
            const float nn = tanh_fast(xn + r * gn);
            const float hnew = (1.f - z) * nn + z * hold;
            // y[m][c], m = b*512 + tt, c = dir*512 + j — nontemporal store
            __builtin_nontemporal_store(
                hnew, &y[((size_t)(bg * 8 + rb) * 512 + tt) * 1024 +
                         dir * 512 + jglob]);
            // h slice, parity t&1 — atomicExch WITH RETURN: ack at L3 =>
            // after vmcnt(0) (inside __syncthreads) this word is visible
            // to every sc1 reader. No fence needed.
            float old = __hip_atomic_exchange(
                &hglob[(size_t)(((t & 1) * 2 + dir) * 4 + bg) * 4096 +
                       (size_t)(jglob >> 2) * 32 + rb * 4 + (jglob & 3)],
                hnew, __ATOMIC_RELAXED, __HIP_MEMORY_SCOPE_AGENT);
            asm volatile("" :: "v"(old));  // keep return alive -> sc0 variant
        }
        __syncthreads();   // all waves drain vmcnt => all swaps completed @L3
        if (tid == 0) {
            __hip_atomic_store(flags + flag_base + jb * 512 + t, 1,
                               __ATOMIC_RELAXED, __HIP_MEMORY_SCOPE_AGENT);
        }
    }
}

// ---------------------------------------------------------------------------
// BatchNorm: partial sums -> finalize (scale/shift). Apply is fused into the
// next layer's GEMM A-load; only the final layer uses bn_apply_k -> d_out.
// ---------------------------------------------------------------------------
__global__ __launch_bounds__(256) void bn_stats_k(
    const float* __restrict__ y, float* __restrict__ part)
{
    const int ct = blockIdx.x;  // 0..7  (c tile of 128)
    const int mc = blockIdx.y;  // 0..31 (m chunk of 512)
    const int tid = threadIdx.x;
    const int c4 = tid & 31, mo = tid >> 5;
    const int cb = ct * 128 + c4 * 4;
    float s0 = 0, s1 = 0, s2 = 0, s3 = 0, q0 = 0, q1 = 0, q2 = 0, q3 = 0;
    for (int m = mc * 512 + mo; m < (mc + 1) * 512; m += 8) {
        const float4 v = *(const float4*)&y[(size_t)m * 1024 + cb];
        s0 += v.x; s1 += v.y; s2 += v.z; s3 += v.w;
        q0 = fmaf(v.x, v.x, q0); q1 = fmaf(v.y, v.y, q1);
        q2 = fmaf(v.z, v.z, q2); q3 = fmaf(v.w, v.w, q3);
    }
    __shared__ float rs[8][128];
    __shared__ float rq[8][128];
    rs[mo][c4 * 4 + 0] = s0; rs[mo][c4 * 4 + 1] = s1;
    rs[mo][c4 * 4 + 2] = s2; rs[mo][c4 * 4 + 3] = s3;
    rq[mo][c4 * 4 + 0] = q0; rq[mo][c4 * 4 + 1] = q1;
    rq[mo][c4 * 4 + 2] = q2; rq[mo][c4 * 4 + 3] = q3;
    __syncthreads();
    if (tid < 128) {
        float S = 0, Q = 0;
#pragma unroll
        for (int i = 0; i < 8; ++i) { S += rs[i][tid]; Q += rq[i][tid]; }
        float* p = &part[((size_t)mc * 1024 + ct * 128 + tid) * 2];
        p[0] = S; p[1] = Q;
    }
}

__global__ __launch_bounds__(256) void bn_final_k(
    const float* __restrict__ part, const float* __restrict__ gamma,
    const float* __restrict__ beta, float* __restrict__ scale,
    float* __restrict__ shift)
{
    const int c = blockIdx.x * 256 + threadIdx.x;
    if (c >= 1024) return;
    float S = 0, Q = 0;
    for (int mc = 0; mc < 32; ++mc) {
        S += part[((size_t)mc * 1024 + c) * 2 + 0];
        Q += part[((size_t)mc * 1024 + c) * 2 + 1];
    }
    const float inv = 1.f / 16384.f;
    const float mean = S * inv;
    const float var = Q * inv - mean * mean;
    const float sc = gamma[c] * rsqrtf(var + 1e-5f);
    scale[c] = sc;
    shift[c] = beta[c] - mean * sc;
}

__global__ __launch_bounds__(256) void bn_apply_k(
    const float* __restrict__ y, const float* __restrict__ scale,
    const float* __restrict__ shift, float* __restrict__ out)
{
    const int n4 = (16384 * 1024) / 4;
    const int stride = gridDim.x * blockDim.x;
    for (int i = blockIdx.x * blockDim.x + threadIdx.x; i < n4; i += stride) {
        const int c4 = i & 255;
        const float4 v = ((const float4*)y)[i];
        const float4 sc = ((const float4*)scale)[c4];
        const float4 sh = ((const float4*)shift)[c4];
        float4 o;
        o.x = fmaf(v.x, sc.x, sh.x);
        o.y = fmaf(v.y, sc.y, sh.y);
        o.z = fmaf(v.z, sc.z, sh.z);
        o.w = fmaf(v.w, sc.w, sh.w);
        ((float4*)out)[i] = o;
    }
}

// ---------------------------------------------------------------------------
extern "C" void kernel_launch(void* const* d_in, const int* in_sizes, int n_in,
                              void* d_out, int out_size, void* d_ws, size_t ws_size,
                              hipStream_t stream)
{
    (void)in_sizes; (void)n_in; (void)out_size; (void)ws_size;
    const float* x      = (const float*)d_in[0];
    const float* w_ih0  = (const float*)d_in[1];
    const float* w_hh0  = (const float*)d_in[2];
    const float* b_ih0  = (const float*)d_in[3];
    const float* b_hh0  = (const float*)d_in[4];
    const float* w_ih_r = (const float*)d_in[5];
    const float* w_hh_r = (const float*)d_in[6];
    const float* b_ih_r = (const float*)d_in[7];
    const float* b_hh_r = (const float*)d_in[8];
    const float* gamma  = (const float*)d_in[9];
    const float* beta   = (const float*)d_in[10];

    float* ws    = (float*)d_ws;
    float* xg    = ws;                      // 2*32*512*3*512 = 50,331,648 f
    float* y_raw = xg + (size_t)50331648;   // 16,777,216 f
    float* hglob = y_raw + 16777216;        // 65,536 f
    float* part  = hglob + 65536;           // 65,536 f
    float* scale = part + 65536;            // 1,024 f
    float* shift = scale + 1024;            // 1,024 f
    int* flags   = (int*)(shift + 1024);    // 3*2*4*32*512 = 393,216 i
    // total ws use: ~258 MB

    hipMemsetAsync(flags, 0, (size_t)3 * 2 * 4 * 32 * 512 * sizeof(int), stream);

    for (int l = 0; l < 3; ++l) {
        const int K = (l == 0) ? 1280 : 1024;
        const float* Ain = (l == 0) ? x : y_raw;
        const float* sc_in = (l == 0) ? nullptr : scale;   // BN of prev layer
        const float* sh_in = (l == 0) ? nullptr : shift;
        const float* wih = (l == 0) ? w_ih0 : (w_ih_r + (size_t)(l - 1) * 2 * 1536 * 1024);
        const float* bih = (l == 0) ? b_ih0 : (b_ih_r + (size_t)(l - 1) * 2 * 1536);
        const float* whh = (l == 0) ? w_hh0 : (w_hh_r + (size_t)(l - 1) * 2 * 1536 * 512);
        const float* bhh = (l == 0) ? b_hh0 : (b_hh_r + (size_t)(l - 1) * 2 * 1536);

        gemm_xg<<<dim3(128, 24), 256, 0, stream>>>(Ain, wih, bih, sc_in, sh_in, xg, K);
        scan_gru<<<256, 256, 0, stream>>>(xg, whh, bhh, hglob,
                                          flags + (size_t)l * 2 * 4 * 32 * 512, y_raw);
        bn_stats_k<<<dim3(8, 32), 256, 0, stream>>>(y_raw, part);
        bn_final_k<<<4, 256, 0, stream>>>(part, gamma + l * 1024, beta + l * 1024,
                                          scale, shift);
        if (l == 2)
            bn_apply_k<<<2048, 256, 0, stream>>>(y_raw, scale, shift, (float*)d_out);
    }
}